// Round 1
// baseline (345.709 us; speedup 1.0000x reference)
//
#include <hip/hip_runtime.h>

#define BATCH 64
#define MGT 300
#define NCLS 20
#define IMG 480.0f

// Anchors per scale (compile-time constants, no runtime copies needed).
__constant__ float c_aw[3][3] = {{10.f, 16.f, 33.f}, {30.f, 62.f, 59.f}, {116.f, 156.f, 373.f}};
__constant__ float c_ah[3][3] = {{13.f, 30.f, 23.f}, {45.f, 45.f, 119.f}, {90.f, 198.f, 326.f}};
// NOTE: careful — scale1 anchors are (30,61),(62,45),(59,119). Fix ah table below.

__constant__ float c_ah_fix[3][3] = {{13.f, 30.f, 23.f}, {61.f, 45.f, 119.f}, {90.f, 198.f, 326.f}};

__device__ __forceinline__ float wave_red(float v) {
    #pragma unroll
    for (int o = 32; o > 0; o >>= 1) v += __shfl_down(v, o, 64);
    return v;
}

// One thread per (b, m) ground truth: compute validity, best anchor per scale,
// cell index per scale, and atomicMax the gt index m into the winner array
// (last-write-wins == max m for duplicate cells).
__global__ void assign_kernel(const float* __restrict__ gt,
                              int* __restrict__ win0, int* __restrict__ win1, int* __restrict__ win2) {
    int t = blockIdx.x * blockDim.x + threadIdx.x;
    if (t >= BATCH * MGT) return;
    int b = t / MGT;
    int m = t - b * MGT;
    const float* g = gt + (size_t)t * 25;
    if (!(g[4] > 0.5f)) return;
    float mx = g[0], my = g[1];
    float w = g[2] * IMG, h = g[3] * IMG;
    float wh = w * h;

    const int Gs[3] = {60, 30, 15};
    int* wins[3] = {win0, win1, win2};
    #pragma unroll
    for (int s = 0; s < 3; ++s) {
        int G = Gs[s];
        int gx = (int)floorf(mx * (float)G);
        int gy = (int)floorf(my * (float)G);
        gx = min(max(gx, 0), G - 1);
        gy = min(max(gy, 0), G - 1);
        float bestR = -1.0f;
        int best = 0;
        #pragma unroll
        for (int a = 0; a < 3; ++a) {
            float aw = c_aw[s][a], ah = c_ah_fix[s][a];
            float inter = fminf(w, aw) * fminf(h, ah);
            float uni = wh + aw * ah - inter;
            float r = inter / (uni + 1e-16f);
            if (r > bestR) { bestR = r; best = a; }  // strict > : first index wins ties (argmax)
        }
        int cell = ((b * 3 + best) * G + gy) * G + gx;
        atomicMax(&wins[s][cell], m);
    }
}

// One thread per cell. Non-winner cells: only the noObj BCE on pconf.
// Winner cells: recompute targets from the winning GT and do full loss.
__global__ __launch_bounds__(256) void loss_kernel(const float* __restrict__ pred,
                                                   const float* __restrict__ gt,
                                                   const int* __restrict__ win,
                                                   int G, int s,
                                                   float* __restrict__ out) {
    int n = BATCH * 3 * G * G;
    float coord = 0.f, objL = 0.f, noObjL = 0.f, clsL = 0.f;
    for (int c = blockIdx.x * blockDim.x + threadIdx.x; c < n; c += gridDim.x * blockDim.x) {
        const float* p = pred + (size_t)c * 25;
        float pconf = p[4];
        int m = win[c];
        if (m < 0) {
            // bce(pconf, 0) = -lq
            float lq = (pconf < 1.0f) ? fmaxf(logf(1.0f - pconf), -100.0f) : -100.0f;
            noObjL -= lq;
        } else {
            int gx = c % G;
            int t1 = c / G;
            int gy = t1 % G;
            int t2 = t1 / G;
            int a = t2 % 3;
            int b = t2 / 3;
            const float* g = gt + ((size_t)b * MGT + m) * 25;
            float mx = g[0], my = g[1];
            float w = g[2] * IMG, h = g[3] * IMG;
            float tx = mx * (float)G - (float)gx;
            float ty = my * (float)G - (float)gy;
            float tw = logf(w / c_aw[s][a] + 1e-16f);
            float th = logf(h / c_ah_fix[s][a] + 1e-16f);
            float dx = p[0] - tx, dy = p[1] - ty, dw = p[2] - tw, dh = p[3] - th;
            coord += dx * dx + dy * dy + dw * dw + dh * dh;
            // bce(pconf, 1) = -lp
            float lp = (pconf > 0.0f) ? fmaxf(logf(pconf), -100.0f) : -100.0f;
            objL -= lp;
            #pragma unroll
            for (int k = 0; k < NCLS; ++k) {
                float pc = p[5 + k], tc = g[5 + k];
                float lpk = (pc > 0.0f) ? fmaxf(logf(pc), -100.0f) : -100.0f;
                float lqk = (pc < 1.0f) ? fmaxf(logf(1.0f - pc), -100.0f) : -100.0f;
                clsL -= tc * lpk + (1.0f - tc) * lqk;
            }
        }
    }
    coord *= 5.0f;   // LAMBDA_COORD
    noObjL *= 0.5f;  // LAMBDA_NOOBJ
    // objL *= 1, clsL *= 1

    // block reduction: wave shuffle then LDS across waves
    __shared__ float sm[4][4];
    int lane = threadIdx.x & 63;
    int wid = threadIdx.x >> 6;
    coord = wave_red(coord);
    objL = wave_red(objL);
    noObjL = wave_red(noObjL);
    clsL = wave_red(clsL);
    if (lane == 0) {
        sm[wid][0] = coord; sm[wid][1] = objL; sm[wid][2] = noObjL; sm[wid][3] = clsL;
    }
    __syncthreads();
    if (threadIdx.x == 0) {
        float a0 = 0, a1 = 0, a2 = 0, a3 = 0;
        int nw = (blockDim.x + 63) >> 6;
        for (int i = 0; i < nw; ++i) {
            a0 += sm[i][0]; a1 += sm[i][1]; a2 += sm[i][2]; a3 += sm[i][3];
        }
        atomicAdd(out + 1, a0);
        atomicAdd(out + 2, a1);
        atomicAdd(out + 3, a2);
        atomicAdd(out + 4, a3);
        atomicAdd(out + 0, a0 + a1 + a2 + a3);
    }
}

extern "C" void kernel_launch(void* const* d_in, const int* in_sizes, int n_in,
                              void* d_out, int out_size, void* d_ws, size_t ws_size,
                              hipStream_t stream) {
    const float* p1 = (const float*)d_in[0];  // (64,3,60,60,25)
    const float* p2 = (const float*)d_in[1];  // (64,3,30,30,25)
    const float* p3 = (const float*)d_in[2];  // (64,3,15,15,25)
    const float* gt = (const float*)d_in[3];  // (64,300,25)
    float* out = (float*)d_out;               // 5 floats: total, coord, objL, noObjL, clsL

    // winner arrays in workspace
    int* win0 = (int*)d_ws;                       // 64*3*60*60 = 691200
    int* win1 = win0 + BATCH * 3 * 60 * 60;       // 64*3*30*30 = 172800
    int* win2 = win1 + BATCH * 3 * 30 * 30;       // 64*3*15*15 =  43200
    size_t winBytes = (size_t)(BATCH * 3 * (60 * 60 + 30 * 30 + 15 * 15)) * sizeof(int);

    hipMemsetAsync(d_ws, 0xFF, winBytes, stream);        // winners = -1
    hipMemsetAsync(d_out, 0, out_size * sizeof(float), stream);

    int nGT = BATCH * MGT;
    assign_kernel<<<(nGT + 255) / 256, 256, 0, stream>>>(gt, win0, win1, win2);

    int n0 = BATCH * 3 * 60 * 60;
    int n1 = BATCH * 3 * 30 * 30;
    int n2 = BATCH * 3 * 15 * 15;
    loss_kernel<<<(n0 + 255) / 256, 256, 0, stream>>>(p1, gt, win0, 60, 0, out);
    loss_kernel<<<(n1 + 255) / 256, 256, 0, stream>>>(p2, gt, win1, 30, 1, out);
    loss_kernel<<<(n2 + 255) / 256, 256, 0, stream>>>(p3, gt, win2, 15, 2, out);
}

// Round 2
// 136.597 us; speedup vs baseline: 2.5309x; 2.5309x over previous
//
#include <hip/hip_runtime.h>

#define BATCH 64
#define MGT 300
#define NCLS 20
#define IMG 480.0f

#define N0 (BATCH * 3 * 60 * 60)   // 691200
#define N1 (BATCH * 3 * 30 * 30)   // 172800
#define N2 (BATCH * 3 * 15 * 15)   //  43200
#define NTOT (N0 + N1 + N2)        // 907200

#define LOSS_BLOCKS 2048

// Anchor tables: scale0 (10,13),(16,30),(33,23); scale1 (30,61),(62,45),(59,119); scale2 (116,90),(156,198),(373,326)
__constant__ float c_aw[3][3] = {{10.f, 16.f, 33.f}, {30.f, 62.f, 59.f}, {116.f, 156.f, 373.f}};
__constant__ float c_ah[3][3] = {{13.f, 30.f, 23.f}, {61.f, 45.f, 119.f}, {90.f, 198.f, 326.f}};

__device__ __forceinline__ float wave_red(float v) {
    #pragma unroll
    for (int o = 32; o > 0; o >>= 1) v += __shfl_down(v, o, 64);
    return v;
}

// One thread per (b, m) ground truth: validity, best anchor per scale, cell
// index per scale; atomicMax(gt index m) implements last-write-wins scatter.
__global__ void assign_kernel(const float* __restrict__ gt,
                              int* __restrict__ win0, int* __restrict__ win1, int* __restrict__ win2) {
    int t = blockIdx.x * blockDim.x + threadIdx.x;
    if (t >= BATCH * MGT) return;
    int b = t / MGT;
    int m = t - b * MGT;
    const float* g = gt + (size_t)t * 25;
    if (!(g[4] > 0.5f)) return;
    float mx = g[0], my = g[1];
    float w = g[2] * IMG, h = g[3] * IMG;
    float wh = w * h;

    const int Gs[3] = {60, 30, 15};
    int* wins[3] = {win0, win1, win2};
    #pragma unroll
    for (int s = 0; s < 3; ++s) {
        int G = Gs[s];
        int gx = (int)floorf(mx * (float)G);
        int gy = (int)floorf(my * (float)G);
        gx = min(max(gx, 0), G - 1);
        gy = min(max(gy, 0), G - 1);
        float bestR = -1.0f;
        int best = 0;
        #pragma unroll
        for (int a = 0; a < 3; ++a) {
            float aw = c_aw[s][a], ah = c_ah[s][a];
            float inter = fminf(w, aw) * fminf(h, ah);
            float uni = wh + aw * ah - inter;
            float r = inter / (uni + 1e-16f);
            if (r > bestR) { bestR = r; best = a; }  // strict > : argmax first-wins on ties
        }
        int cell = ((b * 3 + best) * G + gy) * G + gx;
        atomicMax(&wins[s][cell], m);
    }
}

// Fused over all 3 scales. Each block reduces its 4 components and writes
// them to distinct partial slots — zero atomics (R0 lesson: 13.5K same-line
// atomicAdds serialized at one L2 bank gated the whole kernel).
__global__ __launch_bounds__(256) void loss_fused_kernel(
        const float* __restrict__ p1, const float* __restrict__ p2, const float* __restrict__ p3,
        const float* __restrict__ gt,
        const int* __restrict__ win0, const int* __restrict__ win1, const int* __restrict__ win2,
        float* __restrict__ partials) {
    float coord = 0.f, objL = 0.f, noObjL = 0.f, clsL = 0.f;
    for (int c = blockIdx.x * blockDim.x + threadIdx.x; c < NTOT; c += gridDim.x * blockDim.x) {
        const float* pred; const int* win; int G, s, local;
        if (c < N0)            { pred = p1; win = win0; G = 60; s = 0; local = c; }
        else if (c < N0 + N1)  { pred = p2; win = win1; G = 30; s = 1; local = c - N0; }
        else                   { pred = p3; win = win2; G = 15; s = 2; local = c - N0 - N1; }

        const float* p = pred + (size_t)local * 25;
        float pconf = p[4];
        int m = win[local];
        if (m < 0) {
            // bce(pconf, 0) = -log(1-pconf) clamped
            float lq = (pconf < 1.0f) ? fmaxf(logf(1.0f - pconf), -100.0f) : -100.0f;
            noObjL -= lq;
        } else {
            int gx = local % G;
            int t1 = local / G;
            int gy = t1 % G;
            int t2 = t1 / G;
            int a = t2 % 3;
            int b = t2 / 3;
            const float* g = gt + ((size_t)b * MGT + m) * 25;
            float mx = g[0], my = g[1];
            float w = g[2] * IMG, h = g[3] * IMG;
            float tx = mx * (float)G - (float)gx;
            float ty = my * (float)G - (float)gy;
            float tw = logf(w / c_aw[s][a] + 1e-16f);
            float th = logf(h / c_ah[s][a] + 1e-16f);
            float dx = p[0] - tx, dy = p[1] - ty, dw = p[2] - tw, dh = p[3] - th;
            coord += dx * dx + dy * dy + dw * dw + dh * dh;
            float lp = (pconf > 0.0f) ? fmaxf(logf(pconf), -100.0f) : -100.0f;
            objL -= lp;
            #pragma unroll
            for (int k = 0; k < NCLS; ++k) {
                float pc = p[5 + k], tc = g[5 + k];
                float lpk = (pc > 0.0f) ? fmaxf(logf(pc), -100.0f) : -100.0f;
                float lqk = (pc < 1.0f) ? fmaxf(logf(1.0f - pc), -100.0f) : -100.0f;
                clsL -= tc * lpk + (1.0f - tc) * lqk;
            }
        }
    }
    coord *= 5.0f;   // LAMBDA_COORD
    noObjL *= 0.5f;  // LAMBDA_NOOBJ

    __shared__ float sm[4][4];
    int lane = threadIdx.x & 63;
    int wid = threadIdx.x >> 6;
    coord = wave_red(coord);
    objL = wave_red(objL);
    noObjL = wave_red(noObjL);
    clsL = wave_red(clsL);
    if (lane == 0) {
        sm[wid][0] = coord; sm[wid][1] = objL; sm[wid][2] = noObjL; sm[wid][3] = clsL;
    }
    __syncthreads();
    if (threadIdx.x < 4) {
        float a = sm[0][threadIdx.x] + sm[1][threadIdx.x] + sm[2][threadIdx.x] + sm[3][threadIdx.x];
        partials[(size_t)blockIdx.x * 4 + threadIdx.x] = a;  // distinct slots, no atomics
    }
}

// Single block: reduce LOSS_BLOCKS x 4 partials into the 5 outputs.
__global__ __launch_bounds__(256) void finalize_kernel(const float* __restrict__ partials,
                                                       float* __restrict__ out) {
    int lane = threadIdx.x & 63;
    int w = threadIdx.x >> 6;  // wave w reduces component w
    float s = 0.f;
    for (int i = lane; i < LOSS_BLOCKS; i += 64) s += partials[i * 4 + w];
    s = wave_red(s);
    __shared__ float sm[4];
    if (lane == 0) sm[w] = s;
    __syncthreads();
    if (threadIdx.x == 0) {
        float t = sm[0] + sm[1] + sm[2] + sm[3];
        out[0] = t;
        out[1] = sm[0];  // coord
        out[2] = sm[1];  // objL
        out[3] = sm[2];  // noObjL
        out[4] = sm[3];  // clsL
    }
}

extern "C" void kernel_launch(void* const* d_in, const int* in_sizes, int n_in,
                              void* d_out, int out_size, void* d_ws, size_t ws_size,
                              hipStream_t stream) {
    const float* p1 = (const float*)d_in[0];  // (64,3,60,60,25)
    const float* p2 = (const float*)d_in[1];  // (64,3,30,30,25)
    const float* p3 = (const float*)d_in[2];  // (64,3,15,15,25)
    const float* gt = (const float*)d_in[3];  // (64,300,25)
    float* out = (float*)d_out;               // 5 floats: total, coord, objL, noObjL, clsL

    int* win0 = (int*)d_ws;
    int* win1 = win0 + N0;
    int* win2 = win1 + N1;
    float* partials = (float*)(win2 + N2);    // LOSS_BLOCKS*4 floats
    size_t winBytes = (size_t)NTOT * sizeof(int);

    hipMemsetAsync(d_ws, 0xFF, winBytes, stream);  // winners = -1

    int nGT = BATCH * MGT;
    assign_kernel<<<(nGT + 255) / 256, 256, 0, stream>>>(gt, win0, win1, win2);

    loss_fused_kernel<<<LOSS_BLOCKS, 256, 0, stream>>>(p1, p2, p3, gt, win0, win1, win2, partials);
    finalize_kernel<<<1, 256, 0, stream>>>(partials, out);
}